// Round 8
// baseline (52.965 us; speedup 1.0000x reference)
//
#include <hip/hip_runtime.h>

typedef _Float16 f16;
typedef f16 f16x8 __attribute__((ext_vector_type(8)));
typedef float f32x4 __attribute__((ext_vector_type(4)));

constexpr int Bc = 32, Nc = 1024, Dc = 64, Hc = 4, Ec = 16;
constexpr int HP = 1032;   // h_t pitch (f16): rows r,r+8 alias 2-way on b128 reads = free

// ---------------------------------------------------------------------------
// Kernel 1 (unchanged): h = input @ W per head -> f16 transposed + s vectors.
// ---------------------------------------------------------------------------
__global__ __launch_bounds__(256) void gat_proj(const float* __restrict__ input,
                                                const float* __restrict__ W,
                                                const float* __restrict__ a,
                                                f16* __restrict__ h16t,
                                                float* __restrict__ s_src,
                                                float* __restrict__ s_dst) {
    __shared__ float W_lds[Dc * Ec];
    __shared__ float a_lds[2 * Ec];

    const int tid = threadIdx.x;
    const int gid = blockIdx.x * 256 + tid;   // ((b*H + h)*N + n)
    const int n   = gid & (Nc - 1);
    const int bh  = gid >> 10;
    const int hh  = bh & (Hc - 1);
    const int b   = bh >> 2;

    ((float4*)W_lds)[tid] = ((const float4*)(W + hh * Dc * Ec))[tid];
    if (tid < 2 * Ec) a_lds[tid] = a[tid];
    __syncthreads();

    const float4* in_row = (const float4*)(input + ((size_t)b * Nc + n) * Dc);

    float acc[Ec];
#pragma unroll
    for (int e = 0; e < Ec; ++e) acc[e] = 0.f;

#pragma unroll
    for (int d4 = 0; d4 < Dc / 4; ++d4) {
        float4 x = in_row[d4];
        float xs[4] = {x.x, x.y, x.z, x.w};
#pragma unroll
        for (int k = 0; k < 4; ++k) {
            const float xv = xs[k];
            const float* wrow = &W_lds[(d4 * 4 + k) * Ec];
#pragma unroll
            for (int e = 0; e < Ec; ++e) acc[e] = fmaf(xv, wrow[e], acc[e]);
        }
    }

    f16* hb = h16t + (size_t)bh * Ec * HP + n;
#pragma unroll
    for (int e = 0; e < Ec; ++e) hb[e * HP] = (f16)acc[e];

    float sd = 0.f, ss = 0.f;
#pragma unroll
    for (int e = 0; e < Ec; ++e) {
        sd = fmaf(acc[e], a_lds[e], sd);        // a_dst = a[:E]
        ss = fmaf(acc[e], a_lds[Ec + e], ss);   // a_src = a[E:]
    }
    s_dst[gid] = sd;
    s_src[gid] = ss;
}

// ---------------------------------------------------------------------------
// Kernel 2: round-6 fused attn, body repeated `reps` times inside one
// dispatch (identical work each rep -> deterministic, idempotent) so the
// dispatch rises above the harness fill kernels in the rocprof top-5 and we
// finally get real counters. NOTE: no __restrict__ here and runtime `reps`
// so the compiler cannot prove reps redundant and collapse them.
// ---------------------------------------------------------------------------
__global__ __launch_bounds__(512) void gat_attn7(const f16* h16t,
                                                 const float* s_src,
                                                 const float* s_dst,
                                                 float* out,
                                                 int reps) {
    __shared__ alignas(16) f16 h_t[Ec * HP];     // 33 KB
    __shared__ alignas(16) f16 u_lds[Nc];        // 2 KB
    __shared__ alignas(16) f16 v_lds[Nc];        // 2 KB
    __shared__ float red[8];

    const int bh    = blockIdx.x;      // 0..127
    const int ihalf = blockIdx.y;      // 0..1
    const int tid   = threadIdx.x;
    const int lane  = tid & 63;
    const int wave  = tid >> 6;        // 0..7
    const int row   = lane & 15;       // A-row / D-col index
    const int quad  = lane >> 4;       // K-quadrant

    for (int rep = 0; rep < reps; ++rep) {
        __syncthreads();   // rep r+1 staging must not race rep r tail reads

        // ---- stage h_t (2064 float4 chunks) ----
        {
            const float4* src = (const float4*)(h16t + (size_t)bh * Ec * HP);
            float4* dst = (float4*)h_t;
            dst[tid]        = src[tid];
            dst[512 + tid]  = src[512 + tid];
            dst[1024 + tid] = src[1024 + tid];
            dst[1536 + tid] = src[1536 + tid];
            if (tid < 16) dst[2048 + tid] = src[2048 + tid];
        }

        // ---- block max of s_dst ----
        const float sd0 = s_dst[bh * Nc + tid];
        const float sd1 = s_dst[bh * Nc + 512 + tid];
        {
            float m = fmaxf(sd0, sd1);
#pragma unroll
            for (int off = 1; off < 64; off <<= 1) m = fmaxf(m, __shfl_xor(m, off, 64));
            if (lane == 0) red[wave] = m;
        }
        __syncthreads();
        float maxd = red[0];
#pragma unroll
        for (int w = 1; w < 8; ++w) maxd = fmaxf(maxd, red[w]);

        // ---- u, v into LDS ----
        u_lds[tid]       = (f16)__expf(sd0 - maxd);
        u_lds[512 + tid] = (f16)__expf(sd1 - maxd);
        v_lds[tid]       = (f16)__expf(0.2f * (sd0 - maxd));
        v_lds[512 + tid] = (f16)__expf(0.2f * (sd1 - maxd));

        // ---- per-row C_i ----
        const int ibase = ihalf * 512 + wave * 64;
        f16x8 C8[4];
#pragma unroll
        for (int it = 0; it < 4; ++it) {
            const float si = s_src[bh * Nc + ibase + it * 16 + row];
            const float c1 = si + maxd;
            const float Cf = (c1 >= 0.f) ? __expf(-0.8f * c1) : 1.0f;
            const f16 ch = (f16)Cf;
            C8[it] = (f16x8){ch, ch, ch, ch, ch, ch, ch, ch};
        }
        __syncthreads();

        f32x4 accN[4] = {};
        f32x4 accD[4] = {};
        const f16 o1 = (f16)1.f;
        const f16x8 ones = {o1, o1, o1, o1, o1, o1, o1, o1};

        const f16* up = u_lds + quad * 8;
        const f16* vp = v_lds + quad * 8;
        const f16* bp = h_t + row * HP + quad * 8;

#pragma unroll 4
        for (int kt = 0; kt < 32; ++kt) {
            const f16x8 u8 = *(const f16x8*)(up + kt * 32);
            const f16x8 v8 = *(const f16x8*)(vp + kt * 32);
            const f16x8 b8 = *(const f16x8*)(bp + kt * 32);
#pragma unroll
            for (int it = 0; it < 4; ++it) {
                const f16x8 p = __builtin_elementwise_max(u8, C8[it] * v8);
                accN[it] = __builtin_amdgcn_mfma_f32_16x16x32_f16(p, b8,   accN[it], 0, 0, 0);
                accD[it] = __builtin_amdgcn_mfma_f32_16x16x32_f16(p, ones, accD[it], 0, 0, 0);
            }
        }

        // ---- epilogue: D row = quad*4 + r, col = row ----
#pragma unroll
        for (int it = 0; it < 4; ++it) {
#pragma unroll
            for (int r = 0; r < 4; ++r) {
                const float inv = __builtin_amdgcn_rcpf(accD[it][r]);
                const int i = ibase + it * 16 + quad * 4 + r;
                out[((size_t)(bh * Nc + i)) * Ec + row] = accN[it][r] * inv;
            }
        }
    }
}

extern "C" void kernel_launch(void* const* d_in, const int* in_sizes, int n_in,
                              void* d_out, int out_size, void* d_ws, size_t ws_size,
                              hipStream_t stream) {
    const float* input = (const float*)d_in[0];
    // d_in[1] = adj : UNUSED by the reference
    const float* W = (const float*)d_in[2];
    const float* a = (const float*)d_in[3];
    float* out = (float*)d_out;

    char* ws = (char*)d_ws;
    f16*   h16t  = (f16*)(ws);                       // 128*16*1032*2 = 4,227,072 B
    float* s_src = (float*)(ws + 4227072);           // 524,288 B
    float* s_dst = (float*)(ws + 4227072 + 524288);  // 524,288 B

    gat_proj<<<dim3(Bc * Hc * Nc / 256), dim3(256), 0, stream>>>(input, W, a, h16t,
                                                                 s_src, s_dst);
    // DIAGNOSTIC ROUND: 4 identical reps inside one dispatch so the attn
    // kernel exceeds the ~40us harness fill dispatches and shows up in the
    // rocprof top-5 with full counters. Deterministic & idempotent.
    gat_attn7<<<dim3(Bc * Hc, 2), dim3(512), 0, stream>>>(h16t, s_src, s_dst, out, 4);
}

// Round 9
// 26.307 us; speedup vs baseline: 2.0134x; 2.0134x over previous
//
#include <hip/hip_runtime.h>

typedef _Float16 f16;
typedef f16 f16x8 __attribute__((ext_vector_type(8)));
typedef float f32x4 __attribute__((ext_vector_type(4)));

constexpr int Bc = 32, Nc = 1024, Dc = 64, Hc = 4, Ec = 16;
constexpr int HPL = 1032;  // attn LDS h_t pitch (f16) = 129 float4: odd chunk stride

// ---------------------------------------------------------------------------
// Kernel 1: h = input @ W per head -> f16 TRANSPOSED global [bh][e][1024],
// written via LDS transpose + coalesced float4 stores (round-8 lesson:
// the old per-thread 2B scatter at 2KB stride cost ~13us).
// ---------------------------------------------------------------------------
__global__ __launch_bounds__(256) void gat_proj(const float* __restrict__ input,
                                                const float* __restrict__ W,
                                                const float* __restrict__ a,
                                                f16* __restrict__ h16t,
                                                float* __restrict__ s_src,
                                                float* __restrict__ s_dst) {
    __shared__ float W_lds[Dc * Ec];
    __shared__ float a_lds[2 * Ec];
    __shared__ f16 T[Ec][264];          // 256 + 8 pad (row stride 528B = 33*16B)

    const int tid = threadIdx.x;
    const int gid = blockIdx.x * 256 + tid;   // ((b*H + h)*N + n)
    const int n   = gid & (Nc - 1);
    const int bh  = gid >> 10;
    const int hh  = bh & (Hc - 1);
    const int b   = bh >> 2;
    const int n0  = (blockIdx.x & 3) * 256;

    ((float4*)W_lds)[tid] = ((const float4*)(W + hh * Dc * Ec))[tid];
    if (tid < 2 * Ec) a_lds[tid] = a[tid];
    __syncthreads();

    const float4* in_row = (const float4*)(input + ((size_t)b * Nc + n) * Dc);

    float acc[Ec];
#pragma unroll
    for (int e = 0; e < Ec; ++e) acc[e] = 0.f;

#pragma unroll
    for (int d4 = 0; d4 < Dc / 4; ++d4) {
        float4 x = in_row[d4];
        float xs[4] = {x.x, x.y, x.z, x.w};
#pragma unroll
        for (int k = 0; k < 4; ++k) {
            const float xv = xs[k];
            const float* wrow = &W_lds[(d4 * 4 + k) * Ec];
#pragma unroll
            for (int e = 0; e < Ec; ++e) acc[e] = fmaf(xv, wrow[e], acc[e]);
        }
    }

    float sd = 0.f, ss = 0.f;
#pragma unroll
    for (int e = 0; e < Ec; ++e) {
        sd = fmaf(acc[e], a_lds[e], sd);        // a_dst = a[:E]
        ss = fmaf(acc[e], a_lds[Ec + e], ss);   // a_src = a[E:]
    }
    s_dst[gid] = sd;
    s_src[gid] = ss;

    // LDS transpose: lanes n-consecutive -> 128B-contiguous b16 writes
    const int nl = n - n0;
#pragma unroll
    for (int e = 0; e < Ec; ++e) T[e][nl] = (f16)acc[e];
    __syncthreads();

    // coalesced f16 store: 512 float4 chunks, 2 per thread
    f16* gbase = h16t + (size_t)bh * Ec * Nc;
#pragma unroll
    for (int cc = 0; cc < 2; ++cc) {
        const int c  = cc * 256 + tid;
        const int e  = c >> 4;          // 0..31 over both halves -> e = c>>4 (0..15,16..31? no: 512 chunks = 16e x 32nc? )
        const int e2 = c >> 5;          // 512 chunks = 16 e x 32 nc? 256 n = 32 chunks of 8
        const int nc = c & 31;
        (void)e;
        *(float4*)(gbase + (size_t)e2 * Nc + n0 + nc * 8) =
            *(const float4*)(&T[e2][nc * 8]);
    }
}

// ---------------------------------------------------------------------------
// Kernel 2: fused prep + attention. P_ij = max(u_j, C_i*v_j) exactly;
// out = (P @ h) * rcp(P @ 1) via mfma_f32_16x16x32_f16.
// 1024 threads = 16 waves = 4 waves/SIMD (round-8 counters: 2/SIMD serialized
// the ds_read->pk->MFMA chain). Each wave: 2 i-tiles, full K=1024 from LDS.
// ---------------------------------------------------------------------------
__global__ __launch_bounds__(1024) void gat_attn8(const f16* __restrict__ h16t,
                                                  const float* __restrict__ s_src,
                                                  const float* __restrict__ s_dst,
                                                  float* __restrict__ out) {
    __shared__ alignas(16) f16 h_t[Ec * HPL];    // 33 KB (129 float4 per row)
    __shared__ alignas(16) f16 u_lds[Nc];        // 2 KB
    __shared__ alignas(16) f16 v_lds[Nc];        // 2 KB
    __shared__ float red[16];

    const int bh    = blockIdx.x;      // 0..127
    const int ihalf = blockIdx.y;      // 0..1
    const int tid   = threadIdx.x;
    const int lane  = tid & 63;
    const int wave  = tid >> 6;        // 0..15
    const int row   = lane & 15;       // A-row / D-col index
    const int quad  = lane >> 4;       // K-quadrant

    // ---- stage h_t: global [16][128] float4 -> LDS [16][129] float4 ----
    {
        const float4* src = (const float4*)(h16t + (size_t)bh * Ec * Nc);
        float4* dst = (float4*)h_t;
#pragma unroll
        for (int cc = 0; cc < 2; ++cc) {
            const int c  = cc * 1024 + tid;     // 0..2047
            const int e  = c >> 7;
            const int jc = c & 127;
            dst[e * 129 + jc] = src[c];
        }
    }

    // ---- block max of s_dst (identical across blocks of this bh) ----
    const float sd0 = s_dst[bh * Nc + tid];
    {
        float m = sd0;
#pragma unroll
        for (int off = 1; off < 64; off <<= 1) m = fmaxf(m, __shfl_xor(m, off, 64));
        if (lane == 0) red[wave] = m;
    }
    __syncthreads();
    float maxd = red[0];
#pragma unroll
    for (int w = 1; w < 16; ++w) maxd = fmaxf(maxd, red[w]);

    // ---- u, v into LDS ----
    u_lds[tid] = (f16)__expf(sd0 - maxd);
    v_lds[tid] = (f16)__expf(0.2f * (sd0 - maxd));

    // ---- per-row C_i ----
    const int ibase = ihalf * 512 + wave * 32;
    f16x8 C8[2];
#pragma unroll
    for (int it = 0; it < 2; ++it) {
        const float si = s_src[bh * Nc + ibase + it * 16 + row];
        const float c1 = si + maxd;
        const float Cf = (c1 >= 0.f) ? __expf(-0.8f * c1) : 1.0f;
        const f16 ch = (f16)Cf;
        C8[it] = (f16x8){ch, ch, ch, ch, ch, ch, ch, ch};
    }
    __syncthreads();

    f32x4 accN[2] = {};
    f32x4 accD[2] = {};
    const f16 o1 = (f16)1.f;
    const f16x8 ones = {o1, o1, o1, o1, o1, o1, o1, o1};

    const f16* up = u_lds + quad * 8;
    const f16* vp = v_lds + quad * 8;
    const f16* bp = h_t + row * HPL + quad * 8;

#pragma unroll 4
    for (int kt = 0; kt < 32; ++kt) {
        const f16x8 u8 = *(const f16x8*)(up + kt * 32);
        const f16x8 v8 = *(const f16x8*)(vp + kt * 32);
        const f16x8 b8 = *(const f16x8*)(bp + kt * 32);
#pragma unroll
        for (int it = 0; it < 2; ++it) {
            const f16x8 p = __builtin_elementwise_max(u8, C8[it] * v8);
            accN[it] = __builtin_amdgcn_mfma_f32_16x16x32_f16(p, b8,   accN[it], 0, 0, 0);
            accD[it] = __builtin_amdgcn_mfma_f32_16x16x32_f16(p, ones, accD[it], 0, 0, 0);
        }
    }

    // ---- epilogue: D row = quad*4 + r, col = row (m89 C/D layout) ----
#pragma unroll
    for (int it = 0; it < 2; ++it) {
#pragma unroll
        for (int r = 0; r < 4; ++r) {
            const float inv = __builtin_amdgcn_rcpf(accD[it][r]);
            const int i = ibase + it * 16 + quad * 4 + r;
            out[((size_t)(bh * Nc + i)) * Ec + row] = accN[it][r] * inv;
        }
    }
}

extern "C" void kernel_launch(void* const* d_in, const int* in_sizes, int n_in,
                              void* d_out, int out_size, void* d_ws, size_t ws_size,
                              hipStream_t stream) {
    const float* input = (const float*)d_in[0];
    // d_in[1] = adj : UNUSED by the reference
    const float* W = (const float*)d_in[2];
    const float* a = (const float*)d_in[3];
    float* out = (float*)d_out;

    char* ws = (char*)d_ws;
    f16*   h16t  = (f16*)(ws);                       // 128*16*1024*2 = 4,194,304 B
    float* s_src = (float*)(ws + 4194304);           // 524,288 B
    float* s_dst = (float*)(ws + 4194304 + 524288);  // 524,288 B

    gat_proj<<<dim3(Bc * Hc * Nc / 256), dim3(256), 0, stream>>>(input, W, a, h16t,
                                                                 s_src, s_dst);
    gat_attn8<<<dim3(Bc * Hc, 2), dim3(1024), 0, stream>>>(h16t, s_src, s_dst, out);
}